// Round 4
// baseline (1136.882 us; speedup 1.0000x reference)
//
#include <hip/hip_runtime.h>

typedef unsigned short u16;
typedef float f32x2 __attribute__((ext_vector_type(2)));
typedef float f32x4 __attribute__((ext_vector_type(4)));
typedef __bf16 bf16x8 __attribute__((ext_vector_type(8)));
typedef u16 u16x4 __attribute__((ext_vector_type(4)));

__device__ __forceinline__ u16 f2bf(float f){
  __bf16 h = (__bf16)f;               // native RNE cvt -> v_cvt_pk_bf16_f32 pairs
  union { __bf16 h; u16 u; } x; x.h = h;
  return x.u;
}
__device__ __forceinline__ float bf2f(u16 s){
  union { unsigned u; float f; } x; x.u = ((unsigned)s) << 16;
  return x.f;
}
__device__ __forceinline__ f32x4 mfma16(bf16x8 a, bf16x8 b, f32x4 c){
  return __builtin_amdgcn_mfma_f32_16x16x32_bf16(a, b, c, 0, 0, 0);
}
__device__ __forceinline__ float wred_sum(float x){
  #pragma unroll
  for (int m = 1; m < 64; m <<= 1) x += __shfl_xor(x, m);
  return x;
}
__device__ __forceinline__ float gelu_f(float v){
  return 0.5f * v * (1.0f + erff(v * 0.70710678118654752440f));
}
// linspace(0,3840,256).astype(int32): proven equal to floor(3840*r/255)
__device__ __forceinline__ int sample_idx(int r){
  return (r < 256) ? (3840 * r) / 255 : (3584 + r);   // 3840 + (r-256)
}

// ---------------- K0: transpose+bf16 weights, zero loss slot ----------------
__global__ __launch_bounds__(256) void k_prep(
    const float* __restrict__ in_w, const float* __restrict__ q_w,
    const float* __restrict__ k_w, const float* __restrict__ v_w,
    const float* __restrict__ w1, const float* __restrict__ w2,
    u16* __restrict__ in_wT, u16* __restrict__ q_wT, u16* __restrict__ k_wT,
    u16* __restrict__ v_wT, u16* __restrict__ w1T, u16* __restrict__ w2T,
    float* __restrict__ loss_slot)
{
  __shared__ float tile[64][65];
  int id = blockIdx.x;
  const float* src; u16* dst; int R, C, t;
  if (id < 256)      { src=in_w; dst=in_wT; R=4096; C=256; t=id; }
  else if (id < 272) { src=q_w;  dst=q_wT;  R=256;  C=256; t=id-256; }
  else if (id < 288) { src=k_w;  dst=k_wT;  R=256;  C=256; t=id-272; }
  else if (id < 304) { src=v_w;  dst=v_wT;  R=256;  C=256; t=id-288; }
  else if (id < 336) { src=w1;   dst=w1T;   R=256;  C=512; t=id-304; }
  else               { src=w2;   dst=w2T;   R=512;  C=256; t=id-336; }
  int tC = C >> 6;
  int r0 = (t / tC) * 64, c0 = (t % tC) * 64;
  int tr = threadIdx.x >> 6, tc = threadIdx.x & 63;
  #pragma unroll
  for (int rr = tr; rr < 64; rr += 4)
    tile[rr][tc] = src[(size_t)(r0+rr)*C + c0 + tc];
  __syncthreads();
  #pragma unroll
  for (int cc = tr; cc < 64; cc += 4)
    dst[(size_t)(c0+cc)*R + r0 + tc] = f2bf(tile[tc][cc]);
  if (id == 0 && threadIdx.x == 0) *loss_slot = 0.f;
}

// ---------------- K1: partial column sums of hidden_states ----------------
__global__ __launch_bounds__(256) void k_colsum(const float* __restrict__ hs,
                                                float* __restrict__ parts)
{
  int tc = blockIdx.x;            // 64 chunks of 64 rows
  int hb = blockIdx.y;            // 4 blocks of 1024 cols
  int b  = blockIdx.z;            // 8
  int h0 = hb*1024 + threadIdx.x*4;
  const float* p = hs + ((size_t)b*4096 + (size_t)tc*64)*4096 + h0;
  f32x4 s = {0.f,0.f,0.f,0.f};
  for (int t = 0; t < 64; ++t)
    s += *reinterpret_cast<const f32x4*>(p + (size_t)t*4096);
  *reinterpret_cast<f32x4*>(parts + ((size_t)(b*64+tc) << 12) + h0) = s;
}

// ------- K3: x = LN(sampled @ in_w + in_b), gather fused, bf16 out -------
// 1024 threads = 16 waves (4/SIMD); wave w owns one 16-col MFMA tile.
__global__ __launch_bounds__(1024) void k_in_gemm_ln(
    const float* __restrict__ hs, const u16* __restrict__ in_wT,
    const float* __restrict__ in_b,
    const float* __restrict__ ln_g, const float* __restrict__ ln_b,
    u16* __restrict__ x_b)
{
  __shared__ float xt[16][260];
  const int lane = threadIdx.x & 63;
  const int w = threadIdx.x >> 6;         // 16 waves = 16 col groups of 16
  const int c16 = lane & 15, g4 = lane >> 4;
  const int m0 = blockIdx.x * 16;
  const int row = m0 + c16;
  const int b = row >> 9;
  const int tok = row & 511;
  const int src = sample_idx(tok);
  const float* arow = hs + ((size_t)b*4096 + src)*4096 + g4*8;
  const u16* bcol = in_wT + (size_t)(w*16 + c16)*4096 + g4*8;

  f32x4 acc = {0.f,0.f,0.f,0.f};

  #pragma unroll 4
  for (int k0 = 0; k0 < 4096; k0 += 32) {
    f32x4 a0 = *reinterpret_cast<const f32x4*>(arow + k0);
    f32x4 a1 = *reinterpret_cast<const f32x4*>(arow + k0 + 4);
    bf16x8 bf = *reinterpret_cast<const bf16x8*>(bcol + k0);
    union { u16 u[8]; bf16x8 v; } af;
    #pragma unroll
    for (int i=0;i<4;++i){ af.u[i] = f2bf(a0[i]); af.u[4+i] = f2bf(a1[i]); }
    acc = mfma16(af.v, bf, acc);
  }
  {
    int col = w*16 + c16;
    float bias = in_b[col];
    #pragma unroll
    for (int i=0;i<4;++i) xt[g4*4+i][col] = acc[i] + bias;
  }
  __syncthreads();
  {
    int r = w;   // wave w handles row w
    f32x4 v = *reinterpret_cast<const f32x4*>(&xt[r][4*lane]);
    float s = v[0]+v[1]+v[2]+v[3];
    float q = v[0]*v[0]+v[1]*v[1]+v[2]*v[2]+v[3]*v[3];
    s = wred_sum(s); q = wred_sum(q);
    float mu = s*(1.0f/256.0f);
    float var = q*(1.0f/256.0f) - mu*mu;
    float rs = rsqrtf(var + 1e-5f);
    u16x4 pk;
    #pragma unroll
    for (int i=0;i<4;++i) pk[i] = f2bf((v[i]-mu)*rs*ln_g[4*lane+i] + ln_b[4*lane+i]);
    *reinterpret_cast<u16x4*>(x_b + (size_t)(m0 + r)*256 + 4*lane) = pk;
  }
}

// ------------- K4: k = x@k_w (row-major), v = x@v_w (transposed) -------------
__global__ __launch_bounds__(256) void k_kv(
    const u16* __restrict__ x_b, const u16* __restrict__ k_wT, const u16* __restrict__ v_wT,
    u16* __restrict__ k_out, u16* __restrict__ vT_out)
{
  const int lane = threadIdx.x & 63;
  const int w = threadIdx.x >> 6;
  const int c16 = lane & 15, g4 = lane >> 4;
  const int m0 = blockIdx.x * 16;
  const u16* aptr = x_b + (size_t)(m0 + c16)*256 + g4*8;
  f32x4 ak[4], av[4];
  #pragma unroll
  for (int ct=0; ct<4; ++ct){ ak[ct]=(f32x4){0.f,0.f,0.f,0.f}; av[ct]=(f32x4){0.f,0.f,0.f,0.f}; }
  #pragma unroll
  for (int kk=0; kk<8; ++kk){
    bf16x8 af = *reinterpret_cast<const bf16x8*>(aptr + kk*32);
    #pragma unroll
    for (int ct=0; ct<4; ++ct){
      int col = w*64 + ct*16 + c16;
      bf16x8 bk = *reinterpret_cast<const bf16x8*>(k_wT + (size_t)col*256 + kk*32 + g4*8);
      bf16x8 bv = *reinterpret_cast<const bf16x8*>(v_wT + (size_t)col*256 + kk*32 + g4*8);
      ak[ct] = mfma16(af, bk, ak[ct]);
      av[ct] = mfma16(af, bv, av[ct]);
    }
  }
  const int b = m0 >> 9;
  const int tok0 = (m0 & 511) + g4*4;
  #pragma unroll
  for (int ct=0; ct<4; ++ct){
    int col = w*64 + ct*16 + c16;
    #pragma unroll
    for (int i=0;i<4;++i)
      k_out[(size_t)(m0 + g4*4 + i)*256 + col] = f2bf(ak[ct][i]);
    u16x4 pk;
    #pragma unroll
    for (int i=0;i<4;++i) pk[i] = f2bf(av[ct][i]);
    *reinterpret_cast<u16x4*>(vT_out + ((size_t)(b*256 + col))*512 + tok0) = pk;
  }
}

// ---------------- K5: fused 3-iteration slot-attention loop ----------------
__global__ __launch_bounds__(1024) void k_slots(
    const float* __restrict__ old_slots,
    const u16* __restrict__ k_b, const u16* __restrict__ vT_b,
    const u16* __restrict__ q_wT, const u16* __restrict__ w1T, const u16* __restrict__ w2T,
    const float* __restrict__ ln_s_g, const float* __restrict__ ln_s_b,
    const float* __restrict__ ln_m_g, const float* __restrict__ ln_m_b,
    const float* __restrict__ mlp_b1, const float* __restrict__ mlp_b2,
    float* __restrict__ out_slots)
{
  __shared__ u16 bufA[16*264];    // s_b -> h_b -> ns_b
  __shared__ u16 qS[16*264];
  __shared__ u16 wideS[16*520];   // attn -> g1
  __shared__ u16 updS[16*264];

  const int lane = threadIdx.x & 63;
  const int w    = threadIdx.x >> 6;   // wave w owns slot-row w
  const int c16  = lane & 15;
  const int g4   = lane >> 4;
  const int b    = blockIdx.x;

  const u16* kb = k_b  + (size_t)b * 512 * 256;
  const u16* vb = vT_b + (size_t)b * 256 * 512;

  float sl[4];
  {
    const float* p = old_slots + ((size_t)b*16 + w)*256 + 4*lane;
    #pragma unroll
    for (int i=0;i<4;++i) sl[i] = p[i];
  }
  float lsg[4], lsbv[4], lmg[4], lmb[4];
  #pragma unroll
  for (int i=0;i<4;++i){
    lsg[i]  = ln_s_g[4*lane+i];
    lsbv[i] = ln_s_b[4*lane+i];
    lmg[i]  = ln_m_g[4*lane+i];
    lmb[i]  = ln_m_b[4*lane+i];
  }
  const float b1a = mlp_b1[32*w + c16];
  const float b1b = mlp_b1[32*w + 16 + c16];
  const float b2c = mlp_b2[16*w + c16];
  float sv[4];

  for (int it = 0; it < 3; ++it) {
    // 1. s = LN(slots)
    {
      float s = sl[0]+sl[1]+sl[2]+sl[3];
      float q = sl[0]*sl[0]+sl[1]*sl[1]+sl[2]*sl[2]+sl[3]*sl[3];
      s = wred_sum(s); q = wred_sum(q);
      float mu = s * (1.0f/256.0f);
      float var = q * (1.0f/256.0f) - mu*mu;
      float rs = rsqrtf(var + 1e-5f);
      u16x4 pk;
      #pragma unroll
      for (int i=0;i<4;++i){ sv[i] = (sl[i]-mu)*rs*lsg[i] + lsbv[i]; pk[i] = f2bf(sv[i]); }
      *reinterpret_cast<u16x4*>(bufA + w*264 + 4*lane) = pk;
    }
    __syncthreads();

    // 2. q = s @ q_w   (wave w -> cols 16w..16w+15)
    {
      f32x4 acc = {0.f,0.f,0.f,0.f};
      #pragma unroll
      for (int kk = 0; kk < 8; ++kk) {
        bf16x8 af = *reinterpret_cast<const bf16x8*>(bufA + c16*264 + kk*32 + g4*8);
        bf16x8 bf = *reinterpret_cast<const bf16x8*>(q_wT + (size_t)(16*w + c16)*256 + kk*32 + g4*8);
        acc = mfma16(af, bf, acc);
      }
      #pragma unroll
      for (int i=0;i<4;++i) qS[(g4*4+i)*264 + 16*w + c16] = f2bf(acc[i]);
    }
    __syncthreads();

    // 3. logits = q@k^T * scale; softmax over slot axis (rows); -> attn (bf16)
    {
      bf16x8 qf[8];
      #pragma unroll
      for (int kk=0;kk<8;++kk)
        qf[kk] = *reinterpret_cast<const bf16x8*>(qS + c16*264 + kk*32 + g4*8);
      #pragma unroll
      for (int ct=0; ct<2; ++ct) {
        int n0 = 32*w + 16*ct;
        f32x4 acc = {0.f,0.f,0.f,0.f};
        #pragma unroll
        for (int kk=0;kk<8;++kk){
          bf16x8 bf = *reinterpret_cast<const bf16x8*>(kb + (size_t)(n0 + c16)*256 + kk*32 + g4*8);
          acc = mfma16(qf[kk], bf, acc);
        }
        float t0 = acc[0]*0.0625f, t1 = acc[1]*0.0625f, t2 = acc[2]*0.0625f, t3 = acc[3]*0.0625f;
        float mx = fmaxf(fmaxf(t0,t1), fmaxf(t2,t3));
        mx = fmaxf(mx, __shfl_xor(mx,16));
        mx = fmaxf(mx, __shfl_xor(mx,32));
        float e0 = expf(t0-mx), e1 = expf(t1-mx), e2 = expf(t2-mx), e3 = expf(t3-mx);
        float ss = e0+e1+e2+e3;
        ss += __shfl_xor(ss,16);
        ss += __shfl_xor(ss,32);
        float inv = 1.0f/ss;
        wideS[(g4*4+0)*520 + n0 + c16] = f2bf(e0*inv);
        wideS[(g4*4+1)*520 + n0 + c16] = f2bf(e1*inv);
        wideS[(g4*4+2)*520 + n0 + c16] = f2bf(e2*inv);
        wideS[(g4*4+3)*520 + n0 + c16] = f2bf(e3*inv);
      }
    }
    __syncthreads();

    // 4. upd = attn @ v   (wave w -> d cols 16w..16w+15)
    {
      f32x4 acc = {0.f,0.f,0.f,0.f};
      #pragma unroll
      for (int kk=0; kk<16; ++kk){
        bf16x8 af = *reinterpret_cast<const bf16x8*>(wideS + c16*520 + kk*32 + g4*8);
        bf16x8 bf = *reinterpret_cast<const bf16x8*>(vb + (size_t)(16*w + c16)*512 + kk*32 + g4*8);
        acc = mfma16(af, bf, acc);
      }
      #pragma unroll
      for (int i=0;i<4;++i) updS[(g4*4+i)*264 + 16*w + c16] = f2bf(acc[i]);
    }
    __syncthreads();

    // 5. h = LN(upd), row w
    {
      u16x4 up = *reinterpret_cast<const u16x4*>(updS + w*264 + 4*lane);
      float uv[4];
      #pragma unroll
      for (int i=0;i<4;++i) uv[i] = bf2f(up[i]);
      float s = uv[0]+uv[1]+uv[2]+uv[3];
      float q = uv[0]*uv[0]+uv[1]*uv[1]+uv[2]*uv[2]+uv[3]*uv[3];
      s = wred_sum(s); q = wred_sum(q);
      float mu = s*(1.0f/256.0f);
      float var = q*(1.0f/256.0f) - mu*mu;
      float rs = rsqrtf(var + 1e-5f);
      u16x4 pk;
      #pragma unroll
      for (int i=0;i<4;++i) pk[i] = f2bf((uv[i]-mu)*rs*lmg[i] + lmb[i]);
      *reinterpret_cast<u16x4*>(bufA + w*264 + 4*lane) = pk;
    }
    __syncthreads();

    // 6. g1 = gelu(h @ w1 + b1)  (N=512; wave w -> cols 32w..32w+31)
    {
      bf16x8 hf[8];
      #pragma unroll
      for (int kk=0;kk<8;++kk)
        hf[kk] = *reinterpret_cast<const bf16x8*>(bufA + c16*264 + kk*32 + g4*8);
      #pragma unroll
      for (int ct=0; ct<2; ++ct){
        int n0 = 32*w + 16*ct;
        float bb = ct ? b1b : b1a;
        f32x4 acc = {0.f,0.f,0.f,0.f};
        #pragma unroll
        for (int kk=0;kk<8;++kk){
          bf16x8 bf = *reinterpret_cast<const bf16x8*>(w1T + (size_t)(n0 + c16)*256 + kk*32 + g4*8);
          acc = mfma16(hf[kk], bf, acc);
        }
        #pragma unroll
        for (int i=0;i<4;++i)
          wideS[(g4*4+i)*520 + n0 + c16] = f2bf(gelu_f(acc[i] + bb));
      }
    }
    __syncthreads();

    // 7. out2 = g1 @ w2 + b2;  slots = s + out2
    {
      f32x4 acc = {0.f,0.f,0.f,0.f};
      #pragma unroll
      for (int kk=0; kk<16; ++kk){
        bf16x8 af = *reinterpret_cast<const bf16x8*>(wideS + c16*520 + kk*32 + g4*8);
        bf16x8 bf = *reinterpret_cast<const bf16x8*>(w2T + (size_t)(16*w + c16)*512 + kk*32 + g4*8);
        acc = mfma16(af, bf, acc);
      }
      #pragma unroll
      for (int i=0;i<4;++i) bufA[(g4*4+i)*264 + 16*w + c16] = f2bf(acc[i] + b2c);
    }
    __syncthreads();
    {
      u16x4 ns = *reinterpret_cast<const u16x4*>(bufA + w*264 + 4*lane);
      #pragma unroll
      for (int i=0;i<4;++i) sl[i] = sv[i] + bf2f(ns[i]);
    }
    __syncthreads();
  }

  {
    float* p = out_slots + ((size_t)b*16 + w)*256 + 4*lane;
    #pragma unroll
    for (int i=0;i<4;++i) p[i] = sl[i];
  }
}

// ---------------- K6: decoder stages 1-2 (per slot-row) ----------------
__global__ __launch_bounds__(256) void k_dec(
    const float* __restrict__ slots, const float* __restrict__ w1, const float* __restrict__ b1,
    const float* __restrict__ w2, const float* __restrict__ b2, float* __restrict__ r2g)
{
  __shared__ float sr[256];
  __shared__ float r1[512];
  const int row = blockIdx.x;    // 128 = 8*16
  const int t = threadIdx.x;
  sr[t] = slots[(size_t)row*256 + t];
  __syncthreads();
  float a0 = b1[t], a1 = b1[t+256];
  for (int i=0;i<256;++i){
    float s = sr[i];
    a0 = fmaf(s, w1[(size_t)i*512 + t], a0);
    a1 = fmaf(s, w1[(size_t)i*512 + t + 256], a1);
  }
  r1[t] = gelu_f(a0); r1[t+256] = gelu_f(a1);
  __syncthreads();
  float c0 = b2[t], c1 = b2[t+256];
  for (int i=0;i<512;++i){
    float s = r1[i];
    c0 = fmaf(s, w2[(size_t)i*512 + t], c0);
    c1 = fmaf(s, w2[(size_t)i*512 + t + 256], c1);
  }
  r2g[(size_t)row*512 + t]       = gelu_f(c0);
  r2g[(size_t)row*512 + t + 256] = gelu_f(c1);
}

// -------- K7a: rpart[jc][b][h] = (b3 if jc==0) + sum_{j in chunk} rb[b][j]*w3[j][h]
// grid (jc=8, hb=8): w3 read exactly once; all 8 batches per block.
__global__ __launch_bounds__(256) void k_loss_part(
    const float* __restrict__ r2g, const float* __restrict__ w3, const float* __restrict__ b3,
    float* __restrict__ rpart)
{
  __shared__ float rb[8][64];
  const int jc = blockIdx.x;   // 8 chunks of 64 j
  const int hb = blockIdx.y;   // 8 chunks of 512 h
  const int t  = threadIdx.x;
  const int j0 = jc*64;
  #pragma unroll
  for (int e = t; e < 512; e += 256){
    int b = e >> 6, jj = e & 63;
    float s = 0.f;
    #pragma unroll
    for (int k2=0;k2<16;++k2) s += r2g[(size_t)(b*16 + k2)*512 + j0 + jj];
    rb[b][jj] = s * (1.0f/16.0f);
  }
  __syncthreads();
  const int h = hb*512 + t*2;
  f32x2 acc[8];
  if (jc == 0){
    f32x2 bv = *reinterpret_cast<const f32x2*>(b3 + h);
    #pragma unroll
    for (int b=0;b<8;++b) acc[b] = bv;
  } else {
    #pragma unroll
    for (int b=0;b<8;++b) acc[b] = (f32x2){0.f,0.f};
  }
  for (int j=0;j<64;++j){
    f32x2 wv = *reinterpret_cast<const f32x2*>(w3 + (size_t)(j0+j)*4096 + h);
    #pragma unroll
    for (int b=0;b<8;++b){
      float rj = rb[b][j];
      acc[b][0] = fmaf(rj, wv[0], acc[b][0]);
      acc[b][1] = fmaf(rj, wv[1], acc[b][1]);
    }
  }
  #pragma unroll
  for (int b=0;b<8;++b)
    *reinterpret_cast<f32x2*>(rpart + (((size_t)jc*8 + b) << 12) + h) = acc[b];
}

// -------- K7b: recon = sum_jc rpart; target = parts-sum/4096; loss --------
__global__ __launch_bounds__(256) void k_loss_final(
    const float* __restrict__ rpart, const float* __restrict__ parts,
    float* __restrict__ loss)
{
  __shared__ float red[4];
  int i = blockIdx.x*256 + threadIdx.x;   // 32768
  int b = i >> 12, h = i & 4095;
  float tg = 0.f;
  for (int c = 0; c < 64; ++c) tg += parts[((size_t)(b*64+c) << 12) + h];
  tg *= (1.0f/4096.0f);
  float r = 0.f;
  #pragma unroll
  for (int jc=0; jc<8; ++jc) r += rpart[(((size_t)jc*8 + b) << 12) + h];
  float d = r - tg;
  float loc = wred_sum(d*d);
  const int lane = threadIdx.x & 63, wv_ = threadIdx.x >> 6;
  if (lane == 0) red[wv_] = loc;
  __syncthreads();
  if (threadIdx.x == 0){
    float s = (red[0]+red[1]+red[2]+red[3]) * (1.0f/32768.0f);
    atomicAdd(loss, s);
  }
}

extern "C" void kernel_launch(void* const* d_in, const int* in_sizes, int n_in,
                              void* d_out, int out_size, void* d_ws, size_t ws_size,
                              hipStream_t stream)
{
  const float* hs      = (const float*)d_in[0];
  const float* oslots  = (const float*)d_in[1];
  const float* in_w    = (const float*)d_in[2];
  const float* in_b    = (const float*)d_in[3];
  const float* ln_in_g = (const float*)d_in[4];
  const float* ln_in_b = (const float*)d_in[5];
  const float* ln_s_g  = (const float*)d_in[6];
  const float* ln_s_b  = (const float*)d_in[7];
  const float* ln_m_g  = (const float*)d_in[8];
  const float* ln_m_b  = (const float*)d_in[9];
  const float* q_w     = (const float*)d_in[10];
  const float* k_w     = (const float*)d_in[11];
  const float* v_w     = (const float*)d_in[12];
  const float* mlp_w1  = (const float*)d_in[13];
  const float* mlp_b1  = (const float*)d_in[14];
  const float* mlp_w2  = (const float*)d_in[15];
  const float* mlp_b2  = (const float*)d_in[16];
  const float* dec_w1  = (const float*)d_in[17];
  const float* dec_b1  = (const float*)d_in[18];
  const float* dec_w2  = (const float*)d_in[19];
  const float* dec_b2  = (const float*)d_in[20];
  const float* dec_w3  = (const float*)d_in[21];
  const float* dec_b3  = (const float*)d_in[22];

  char* ws = (char*)d_ws;
  size_t off = 0;
  auto alloc = [&](size_t bytes)->char*{
    char* p = ws + off; off = (off + bytes + 255) & ~(size_t)255; return p;
  };
  float* parts = (float*)alloc((size_t)8*64*4096*4);
  u16* in_wT = (u16*)alloc((size_t)256*4096*2);
  u16* q_wT  = (u16*)alloc((size_t)65536*2);
  u16* k_wT  = (u16*)alloc((size_t)65536*2);
  u16* v_wT  = (u16*)alloc((size_t)65536*2);
  u16* w1T   = (u16*)alloc((size_t)131072*2);
  u16* w2T   = (u16*)alloc((size_t)131072*2);
  u16* x_b   = (u16*)alloc((size_t)4096*256*2);
  u16* kk_b  = (u16*)alloc((size_t)4096*256*2);
  u16* vT_b  = (u16*)alloc((size_t)8*256*512*2);
  float* r2g = (float*)alloc((size_t)128*512*4);
  float* rpart = (float*)alloc((size_t)64*4096*4);

  float* out_slots = (float*)d_out;
  float* out_loss  = out_slots + 32768;

  hipLaunchKernelGGL(k_prep, dim3(368), dim3(256), 0, stream,
      in_w, q_w, k_w, v_w, mlp_w1, mlp_w2, in_wT, q_wT, k_wT, v_wT, w1T, w2T, out_loss);
  hipLaunchKernelGGL(k_colsum, dim3(64,4,8), dim3(256), 0, stream, hs, parts);
  hipLaunchKernelGGL(k_in_gemm_ln, dim3(256), dim3(1024), 0, stream,
      hs, in_wT, in_b, ln_in_g, ln_in_b, x_b);
  hipLaunchKernelGGL(k_kv, dim3(256), dim3(256), 0, stream, x_b, k_wT, v_wT, kk_b, vT_b);
  hipLaunchKernelGGL(k_slots, dim3(8), dim3(1024), 0, stream,
      oslots, kk_b, vT_b, q_wT, w1T, w2T,
      ln_s_g, ln_s_b, ln_m_g, ln_m_b, mlp_b1, mlp_b2, out_slots);
  hipLaunchKernelGGL(k_dec, dim3(128), dim3(256), 0, stream,
      out_slots, dec_w1, dec_b1, dec_w2, dec_b2, r2g);
  hipLaunchKernelGGL(k_loss_part, dim3(8,8), dim3(256), 0, stream,
      r2g, dec_w3, dec_b3, rpart);
  hipLaunchKernelGGL(k_loss_final, dim3(128), dim3(256), 0, stream,
      rpart, parts, out_loss);
}

// Round 5
// 1052.308 us; speedup vs baseline: 1.0804x; 1.0804x over previous
//
#include <hip/hip_runtime.h>

typedef unsigned short u16;
typedef float f32x2 __attribute__((ext_vector_type(2)));
typedef float f32x4 __attribute__((ext_vector_type(4)));
typedef __bf16 bf16x8 __attribute__((ext_vector_type(8)));
typedef u16 u16x4 __attribute__((ext_vector_type(4)));
typedef u16 u16x8 __attribute__((ext_vector_type(8)));

__device__ __forceinline__ u16 f2bf(float f){
  __bf16 h = (__bf16)f;               // native RNE cvt -> v_cvt_pk_bf16_f32 pairs
  union { __bf16 h; u16 u; } x; x.h = h;
  return x.u;
}
__device__ __forceinline__ float bf2f(u16 s){
  union { unsigned u; float f; } x; x.u = ((unsigned)s) << 16;
  return x.f;
}
__device__ __forceinline__ f32x4 mfma16(bf16x8 a, bf16x8 b, f32x4 c){
  return __builtin_amdgcn_mfma_f32_16x16x32_bf16(a, b, c, 0, 0, 0);
}
__device__ __forceinline__ float wred_sum(float x){
  #pragma unroll
  for (int m = 1; m < 64; m <<= 1) x += __shfl_xor(x, m);
  return x;
}
__device__ __forceinline__ float gelu_f(float v){
  return 0.5f * v * (1.0f + erff(v * 0.70710678118654752440f));
}
// linspace(0,3840,256).astype(int32): proven equal to floor(3840*r/255)
__device__ __forceinline__ int sample_idx(int r){
  return (r < 256) ? (3840 * r) / 255 : (3584 + r);   // 3840 + (r-256)
}

// ---------------- K0: transpose+bf16 weights, zero loss slot ----------------
__global__ __launch_bounds__(256) void k_prep(
    const float* __restrict__ in_w, const float* __restrict__ q_w,
    const float* __restrict__ k_w, const float* __restrict__ v_w,
    const float* __restrict__ w1, const float* __restrict__ w2,
    u16* __restrict__ in_wT, u16* __restrict__ q_wT, u16* __restrict__ k_wT,
    u16* __restrict__ v_wT, u16* __restrict__ w1T, u16* __restrict__ w2T,
    float* __restrict__ loss_slot)
{
  __shared__ float tile[64][65];
  int id = blockIdx.x;
  const float* src; u16* dst; int R, C, t;
  if (id < 256)      { src=in_w; dst=in_wT; R=4096; C=256; t=id; }
  else if (id < 272) { src=q_w;  dst=q_wT;  R=256;  C=256; t=id-256; }
  else if (id < 288) { src=k_w;  dst=k_wT;  R=256;  C=256; t=id-272; }
  else if (id < 304) { src=v_w;  dst=v_wT;  R=256;  C=256; t=id-288; }
  else if (id < 336) { src=w1;   dst=w1T;   R=256;  C=512; t=id-304; }
  else               { src=w2;   dst=w2T;   R=512;  C=256; t=id-336; }
  int tC = C >> 6;
  int r0 = (t / tC) * 64, c0 = (t % tC) * 64;
  int tr = threadIdx.x >> 6, tc = threadIdx.x & 63;
  #pragma unroll
  for (int rr = tr; rr < 64; rr += 4)
    tile[rr][tc] = src[(size_t)(r0+rr)*C + c0 + tc];
  __syncthreads();
  #pragma unroll
  for (int cc = tr; cc < 64; cc += 4)
    dst[(size_t)(c0+cc)*R + r0 + tc] = f2bf(tile[tc][cc]);
  if (id == 0 && threadIdx.x == 0) *loss_slot = 0.f;
}

// ---------------- K1: partial column sums of hidden_states ----------------
__global__ __launch_bounds__(256) void k_colsum(const float* __restrict__ hs,
                                                float* __restrict__ parts)
{
  int tc = blockIdx.x;            // 64 chunks of 64 rows
  int hb = blockIdx.y;            // 4 blocks of 1024 cols
  int b  = blockIdx.z;            // 8
  int h0 = hb*1024 + threadIdx.x*4;
  const float* p = hs + ((size_t)b*4096 + (size_t)tc*64)*4096 + h0;
  f32x4 s = {0.f,0.f,0.f,0.f};
  for (int t = 0; t < 64; ++t)
    s += *reinterpret_cast<const f32x4*>(p + (size_t)t*4096);
  *reinterpret_cast<f32x4*>(parts + ((size_t)(b*64+tc) << 12) + h0) = s;
}

// ------- K3: x = LN(sampled @ in_w + in_b), LDS-staged A, bf16 out -------
// 64 blocks x 1024 threads (16 waves). Block owns 64 rows; wave w owns cols
// 16w..16w+15 (4 row-subtiles). A staged once into LDS (bf16, padded),
// register-prefetched one K-chunk ahead. A read 1x (64 MB), B read 64x
// redundant across blocks (128 MB L2/L3) instead of prior 1.5 GB total.
__global__ __launch_bounds__(1024) void k_in_gemm_ln(
    const float* __restrict__ hs, const u16* __restrict__ in_wT,
    const float* __restrict__ in_b,
    const float* __restrict__ ln_g, const float* __restrict__ ln_b,
    u16* __restrict__ x_b)
{
  __shared__ u16 aS[2][64][136];     // 64 rows x 128 bf16, +8 pad (2-way free)
  __shared__ float xt[64][260];
  const int t = threadIdx.x;
  const int lane = t & 63;
  const int w = t >> 6;              // 16 waves
  const int c16 = lane & 15, g4 = lane >> 4;
  const int m0 = blockIdx.x * 64;

  // staging coords: 16 threads/row, 8 f32 each -> 64 rows x 128 cols
  const int srow = t >> 4;
  const int scol = (t & 15) * 8;
  const int grow = m0 + srow;
  const int gb = grow >> 9, gtok = grow & 511;
  const float* arow_g = hs + ((size_t)gb*4096 + sample_idx(gtok))*4096 + scol;
  const u16* bcol = in_wT + (size_t)(w*16 + c16)*4096;

  f32x4 acc[4];
  #pragma unroll
  for (int rt=0; rt<4; ++rt) acc[rt] = (f32x4){0.f,0.f,0.f,0.f};

  // prologue: stage chunk 0
  f32x4 pa0 = *reinterpret_cast<const f32x4*>(arow_g);
  f32x4 pa1 = *reinterpret_cast<const f32x4*>(arow_g + 4);
  {
    union { u16 u[8]; u16x8 v; } pk;
    #pragma unroll
    for (int i=0;i<4;++i){ pk.u[i] = f2bf(pa0[i]); pk.u[4+i] = f2bf(pa1[i]); }
    *reinterpret_cast<u16x8*>(&aS[0][srow][scol]) = pk.v;
  }
  __syncthreads();

  for (int c = 0; c < 32; ++c) {
    const int cur = c & 1;
    // issue next chunk's global loads (latency hides under MFMA below)
    if (c + 1 < 32) {
      pa0 = *reinterpret_cast<const f32x4*>(arow_g + (c+1)*128);
      pa1 = *reinterpret_cast<const f32x4*>(arow_g + (c+1)*128 + 4);
    }
    // compute this chunk: 4 k-steps x 4 row-subtiles, B-frag reused over rt
    #pragma unroll
    for (int kk = 0; kk < 4; ++kk) {
      bf16x8 bf = *reinterpret_cast<const bf16x8*>(bcol + c*128 + kk*32 + g4*8);
      #pragma unroll
      for (int rt = 0; rt < 4; ++rt) {
        bf16x8 af = *reinterpret_cast<const bf16x8*>(&aS[cur][rt*16 + c16][kk*32 + g4*8]);
        acc[rt] = mfma16(af, bf, acc[rt]);
      }
    }
    // store prefetched chunk to the other buffer
    if (c + 1 < 32) {
      union { u16 u[8]; u16x8 v; } pk;
      #pragma unroll
      for (int i=0;i<4;++i){ pk.u[i] = f2bf(pa0[i]); pk.u[4+i] = f2bf(pa1[i]); }
      *reinterpret_cast<u16x8*>(&aS[cur^1][srow][scol]) = pk.v;
    }
    __syncthreads();
  }

  // epilogue: bias + LN over each row of the 64-row tile
  {
    const int col = w*16 + c16;
    const float bias = in_b[col];
    #pragma unroll
    for (int rt=0; rt<4; ++rt)
      #pragma unroll
      for (int i=0;i<4;++i)
        xt[rt*16 + g4*4 + i][col] = acc[rt][i] + bias;
  }
  __syncthreads();
  #pragma unroll
  for (int rr=0; rr<4; ++rr){
    const int r = 4*w + rr;       // wave w -> rows 4w..4w+3
    f32x4 v = *reinterpret_cast<const f32x4*>(&xt[r][4*lane]);
    float s = v[0]+v[1]+v[2]+v[3];
    float q = v[0]*v[0]+v[1]*v[1]+v[2]*v[2]+v[3]*v[3];
    s = wred_sum(s); q = wred_sum(q);
    float mu = s*(1.0f/256.0f);
    float var = q*(1.0f/256.0f) - mu*mu;
    float rs = rsqrtf(var + 1e-5f);
    u16x4 pk;
    #pragma unroll
    for (int i=0;i<4;++i) pk[i] = f2bf((v[i]-mu)*rs*ln_g[4*lane+i] + ln_b[4*lane+i]);
    *reinterpret_cast<u16x4*>(x_b + (size_t)(m0 + r)*256 + 4*lane) = pk;
  }
}

// ------------- K4: k = x@k_w (row-major), v = x@v_w (transposed) -------------
__global__ __launch_bounds__(256) void k_kv(
    const u16* __restrict__ x_b, const u16* __restrict__ k_wT, const u16* __restrict__ v_wT,
    u16* __restrict__ k_out, u16* __restrict__ vT_out)
{
  const int lane = threadIdx.x & 63;
  const int w = threadIdx.x >> 6;
  const int c16 = lane & 15, g4 = lane >> 4;
  const int m0 = blockIdx.x * 16;
  const u16* aptr = x_b + (size_t)(m0 + c16)*256 + g4*8;
  f32x4 ak[4], av[4];
  #pragma unroll
  for (int ct=0; ct<4; ++ct){ ak[ct]=(f32x4){0.f,0.f,0.f,0.f}; av[ct]=(f32x4){0.f,0.f,0.f,0.f}; }
  #pragma unroll
  for (int kk=0; kk<8; ++kk){
    bf16x8 af = *reinterpret_cast<const bf16x8*>(aptr + kk*32);
    #pragma unroll
    for (int ct=0; ct<4; ++ct){
      int col = w*64 + ct*16 + c16;
      bf16x8 bk = *reinterpret_cast<const bf16x8*>(k_wT + (size_t)col*256 + kk*32 + g4*8);
      bf16x8 bv = *reinterpret_cast<const bf16x8*>(v_wT + (size_t)col*256 + kk*32 + g4*8);
      ak[ct] = mfma16(af, bk, ak[ct]);
      av[ct] = mfma16(af, bv, av[ct]);
    }
  }
  const int b = m0 >> 9;
  const int tok0 = (m0 & 511) + g4*4;
  #pragma unroll
  for (int ct=0; ct<4; ++ct){
    int col = w*64 + ct*16 + c16;
    #pragma unroll
    for (int i=0;i<4;++i)
      k_out[(size_t)(m0 + g4*4 + i)*256 + col] = f2bf(ak[ct][i]);
    u16x4 pk;
    #pragma unroll
    for (int i=0;i<4;++i) pk[i] = f2bf(av[ct][i]);
    *reinterpret_cast<u16x4*>(vT_out + ((size_t)(b*256 + col))*512 + tok0) = pk;
  }
}

// ---------------- K5: fused 3-iteration slot-attention loop ----------------
__global__ __launch_bounds__(1024) void k_slots(
    const float* __restrict__ old_slots,
    const u16* __restrict__ k_b, const u16* __restrict__ vT_b,
    const u16* __restrict__ q_wT, const u16* __restrict__ w1T, const u16* __restrict__ w2T,
    const float* __restrict__ ln_s_g, const float* __restrict__ ln_s_b,
    const float* __restrict__ ln_m_g, const float* __restrict__ ln_m_b,
    const float* __restrict__ mlp_b1, const float* __restrict__ mlp_b2,
    float* __restrict__ out_slots)
{
  __shared__ u16 bufA[16*264];    // s_b -> h_b -> ns_b
  __shared__ u16 qS[16*264];
  __shared__ u16 wideS[16*520];   // attn -> g1
  __shared__ u16 updS[16*264];

  const int lane = threadIdx.x & 63;
  const int w    = threadIdx.x >> 6;   // wave w owns slot-row w
  const int c16  = lane & 15;
  const int g4   = lane >> 4;
  const int b    = blockIdx.x;

  const u16* kb = k_b  + (size_t)b * 512 * 256;
  const u16* vb = vT_b + (size_t)b * 256 * 512;

  float sl[4];
  {
    const float* p = old_slots + ((size_t)b*16 + w)*256 + 4*lane;
    #pragma unroll
    for (int i=0;i<4;++i) sl[i] = p[i];
  }
  float lsg[4], lsbv[4], lmg[4], lmb[4];
  #pragma unroll
  for (int i=0;i<4;++i){
    lsg[i]  = ln_s_g[4*lane+i];
    lsbv[i] = ln_s_b[4*lane+i];
    lmg[i]  = ln_m_g[4*lane+i];
    lmb[i]  = ln_m_b[4*lane+i];
  }
  const float b1a = mlp_b1[32*w + c16];
  const float b1b = mlp_b1[32*w + 16 + c16];
  const float b2c = mlp_b2[16*w + c16];
  float sv[4];

  for (int it = 0; it < 3; ++it) {
    // 1. s = LN(slots)
    {
      float s = sl[0]+sl[1]+sl[2]+sl[3];
      float q = sl[0]*sl[0]+sl[1]*sl[1]+sl[2]*sl[2]+sl[3]*sl[3];
      s = wred_sum(s); q = wred_sum(q);
      float mu = s * (1.0f/256.0f);
      float var = q * (1.0f/256.0f) - mu*mu;
      float rs = rsqrtf(var + 1e-5f);
      u16x4 pk;
      #pragma unroll
      for (int i=0;i<4;++i){ sv[i] = (sl[i]-mu)*rs*lsg[i] + lsbv[i]; pk[i] = f2bf(sv[i]); }
      *reinterpret_cast<u16x4*>(bufA + w*264 + 4*lane) = pk;
    }
    __syncthreads();

    // 2. q = s @ q_w   (wave w -> cols 16w..16w+15)
    {
      f32x4 acc = {0.f,0.f,0.f,0.f};
      #pragma unroll
      for (int kk = 0; kk < 8; ++kk) {
        bf16x8 af = *reinterpret_cast<const bf16x8*>(bufA + c16*264 + kk*32 + g4*8);
        bf16x8 bf = *reinterpret_cast<const bf16x8*>(q_wT + (size_t)(16*w + c16)*256 + kk*32 + g4*8);
        acc = mfma16(af, bf, acc);
      }
      #pragma unroll
      for (int i=0;i<4;++i) qS[(g4*4+i)*264 + 16*w + c16] = f2bf(acc[i]);
    }
    __syncthreads();

    // 3. logits = q@k^T * scale; softmax over slot axis (rows); -> attn (bf16)
    {
      bf16x8 qf[8];
      #pragma unroll
      for (int kk=0;kk<8;++kk)
        qf[kk] = *reinterpret_cast<const bf16x8*>(qS + c16*264 + kk*32 + g4*8);
      #pragma unroll
      for (int ct=0; ct<2; ++ct) {
        int n0 = 32*w + 16*ct;
        f32x4 acc = {0.f,0.f,0.f,0.f};
        #pragma unroll
        for (int kk=0;kk<8;++kk){
          bf16x8 bf = *reinterpret_cast<const bf16x8*>(kb + (size_t)(n0 + c16)*256 + kk*32 + g4*8);
          acc = mfma16(qf[kk], bf, acc);
        }
        float t0 = acc[0]*0.0625f, t1 = acc[1]*0.0625f, t2 = acc[2]*0.0625f, t3 = acc[3]*0.0625f;
        float mx = fmaxf(fmaxf(t0,t1), fmaxf(t2,t3));
        mx = fmaxf(mx, __shfl_xor(mx,16));
        mx = fmaxf(mx, __shfl_xor(mx,32));
        float e0 = expf(t0-mx), e1 = expf(t1-mx), e2 = expf(t2-mx), e3 = expf(t3-mx);
        float ss = e0+e1+e2+e3;
        ss += __shfl_xor(ss,16);
        ss += __shfl_xor(ss,32);
        float inv = 1.0f/ss;
        wideS[(g4*4+0)*520 + n0 + c16] = f2bf(e0*inv);
        wideS[(g4*4+1)*520 + n0 + c16] = f2bf(e1*inv);
        wideS[(g4*4+2)*520 + n0 + c16] = f2bf(e2*inv);
        wideS[(g4*4+3)*520 + n0 + c16] = f2bf(e3*inv);
      }
    }
    __syncthreads();

    // 4. upd = attn @ v   (wave w -> d cols 16w..16w+15)
    {
      f32x4 acc = {0.f,0.f,0.f,0.f};
      #pragma unroll
      for (int kk=0; kk<16; ++kk){
        bf16x8 af = *reinterpret_cast<const bf16x8*>(wideS + c16*520 + kk*32 + g4*8);
        bf16x8 bf = *reinterpret_cast<const bf16x8*>(vb + (size_t)(16*w + c16)*512 + kk*32 + g4*8);
        acc = mfma16(af, bf, acc);
      }
      #pragma unroll
      for (int i=0;i<4;++i) updS[(g4*4+i)*264 + 16*w + c16] = f2bf(acc[i]);
    }
    __syncthreads();

    // 5. h = LN(upd), row w
    {
      u16x4 up = *reinterpret_cast<const u16x4*>(updS + w*264 + 4*lane);
      float uv[4];
      #pragma unroll
      for (int i=0;i<4;++i) uv[i] = bf2f(up[i]);
      float s = uv[0]+uv[1]+uv[2]+uv[3];
      float q = uv[0]*uv[0]+uv[1]*uv[1]+uv[2]*uv[2]+uv[3]*uv[3];
      s = wred_sum(s); q = wred_sum(q);
      float mu = s*(1.0f/256.0f);
      float var = q*(1.0f/256.0f) - mu*mu;
      float rs = rsqrtf(var + 1e-5f);
      u16x4 pk;
      #pragma unroll
      for (int i=0;i<4;++i) pk[i] = f2bf((uv[i]-mu)*rs*lmg[i] + lmb[i]);
      *reinterpret_cast<u16x4*>(bufA + w*264 + 4*lane) = pk;
    }
    __syncthreads();

    // 6. g1 = gelu(h @ w1 + b1)  (N=512; wave w -> cols 32w..32w+31)
    {
      bf16x8 hf[8];
      #pragma unroll
      for (int kk=0;kk<8;++kk)
        hf[kk] = *reinterpret_cast<const bf16x8*>(bufA + c16*264 + kk*32 + g4*8);
      #pragma unroll
      for (int ct=0; ct<2; ++ct){
        int n0 = 32*w + 16*ct;
        float bb = ct ? b1b : b1a;
        f32x4 acc = {0.f,0.f,0.f,0.f};
        #pragma unroll
        for (int kk=0;kk<8;++kk){
          bf16x8 bf = *reinterpret_cast<const bf16x8*>(w1T + (size_t)(n0 + c16)*256 + kk*32 + g4*8);
          acc = mfma16(hf[kk], bf, acc);
        }
        #pragma unroll
        for (int i=0;i<4;++i)
          wideS[(g4*4+i)*520 + n0 + c16] = f2bf(gelu_f(acc[i] + bb));
      }
    }
    __syncthreads();

    // 7. out2 = g1 @ w2 + b2;  slots = s + out2
    {
      f32x4 acc = {0.f,0.f,0.f,0.f};
      #pragma unroll
      for (int kk=0; kk<16; ++kk){
        bf16x8 af = *reinterpret_cast<const bf16x8*>(wideS + c16*520 + kk*32 + g4*8);
        bf16x8 bf = *reinterpret_cast<const bf16x8*>(w2T + (size_t)(16*w + c16)*512 + kk*32 + g4*8);
        acc = mfma16(af, bf, acc);
      }
      #pragma unroll
      for (int i=0;i<4;++i) bufA[(g4*4+i)*264 + 16*w + c16] = f2bf(acc[i] + b2c);
    }
    __syncthreads();
    {
      u16x4 ns = *reinterpret_cast<const u16x4*>(bufA + w*264 + 4*lane);
      #pragma unroll
      for (int i=0;i<4;++i) sl[i] = sv[i] + bf2f(ns[i]);
    }
    __syncthreads();
  }

  {
    float* p = out_slots + ((size_t)b*16 + w)*256 + 4*lane;
    #pragma unroll
    for (int i=0;i<4;++i) p[i] = sl[i];
  }
}

// ---------------- K6: decoder stages 1-2 (per slot-row) ----------------
__global__ __launch_bounds__(256) void k_dec(
    const float* __restrict__ slots, const float* __restrict__ w1, const float* __restrict__ b1,
    const float* __restrict__ w2, const float* __restrict__ b2, float* __restrict__ r2g)
{
  __shared__ float sr[256];
  __shared__ float r1[512];
  const int row = blockIdx.x;    // 128 = 8*16
  const int t = threadIdx.x;
  sr[t] = slots[(size_t)row*256 + t];
  __syncthreads();
  float a0 = b1[t], a1 = b1[t+256];
  for (int i=0;i<256;++i){
    float s = sr[i];
    a0 = fmaf(s, w1[(size_t)i*512 + t], a0);
    a1 = fmaf(s, w1[(size_t)i*512 + t + 256], a1);
  }
  r1[t] = gelu_f(a0); r1[t+256] = gelu_f(a1);
  __syncthreads();
  float c0 = b2[t], c1 = b2[t+256];
  for (int i=0;i<512;++i){
    float s = r1[i];
    c0 = fmaf(s, w2[(size_t)i*512 + t], c0);
    c1 = fmaf(s, w2[(size_t)i*512 + t + 256], c1);
  }
  r2g[(size_t)row*512 + t]       = gelu_f(c0);
  r2g[(size_t)row*512 + t + 256] = gelu_f(c1);
}

// -------- K7a: rpart[jc][b][h] = (b3 if jc==0) + sum_{j in chunk} rb[b][j]*w3[j][h]
// grid (jc=8, hb=8): w3 read exactly once; all 8 batches per block.
__global__ __launch_bounds__(256) void k_loss_part(
    const float* __restrict__ r2g, const float* __restrict__ w3, const float* __restrict__ b3,
    float* __restrict__ rpart)
{
  __shared__ float rb[8][64];
  const int jc = blockIdx.x;   // 8 chunks of 64 j
  const int hb = blockIdx.y;   // 8 chunks of 512 h
  const int t  = threadIdx.x;
  const int j0 = jc*64;
  #pragma unroll
  for (int e = t; e < 512; e += 256){
    int b = e >> 6, jj = e & 63;
    float s = 0.f;
    #pragma unroll
    for (int k2=0;k2<16;++k2) s += r2g[(size_t)(b*16 + k2)*512 + j0 + jj];
    rb[b][jj] = s * (1.0f/16.0f);
  }
  __syncthreads();
  const int h = hb*512 + t*2;
  f32x2 acc[8];
  if (jc == 0){
    f32x2 bv = *reinterpret_cast<const f32x2*>(b3 + h);
    #pragma unroll
    for (int b=0;b<8;++b) acc[b] = bv;
  } else {
    #pragma unroll
    for (int b=0;b<8;++b) acc[b] = (f32x2){0.f,0.f};
  }
  for (int j=0;j<64;++j){
    f32x2 wv = *reinterpret_cast<const f32x2*>(w3 + (size_t)(j0+j)*4096 + h);
    #pragma unroll
    for (int b=0;b<8;++b){
      float rj = rb[b][j];
      acc[b][0] = fmaf(rj, wv[0], acc[b][0]);
      acc[b][1] = fmaf(rj, wv[1], acc[b][1]);
    }
  }
  #pragma unroll
  for (int b=0;b<8;++b)
    *reinterpret_cast<f32x2*>(rpart + (((size_t)jc*8 + b) << 12) + h) = acc[b];
}

// -------- K7b: recon = sum_jc rpart; target = parts-sum/4096; loss --------
__global__ __launch_bounds__(256) void k_loss_final(
    const float* __restrict__ rpart, const float* __restrict__ parts,
    float* __restrict__ loss)
{
  __shared__ float red[4];
  int i = blockIdx.x*256 + threadIdx.x;   // 32768
  int b = i >> 12, h = i & 4095;
  float tg = 0.f;
  for (int c = 0; c < 64; ++c) tg += parts[((size_t)(b*64+c) << 12) + h];
  tg *= (1.0f/4096.0f);
  float r = 0.f;
  #pragma unroll
  for (int jc=0; jc<8; ++jc) r += rpart[(((size_t)jc*8 + b) << 12) + h];
  float d = r - tg;
  float loc = wred_sum(d*d);
  const int lane = threadIdx.x & 63, wv_ = threadIdx.x >> 6;
  if (lane == 0) red[wv_] = loc;
  __syncthreads();
  if (threadIdx.x == 0){
    float s = (red[0]+red[1]+red[2]+red[3]) * (1.0f/32768.0f);
    atomicAdd(loss, s);
  }
}

extern "C" void kernel_launch(void* const* d_in, const int* in_sizes, int n_in,
                              void* d_out, int out_size, void* d_ws, size_t ws_size,
                              hipStream_t stream)
{
  const float* hs      = (const float*)d_in[0];
  const float* oslots  = (const float*)d_in[1];
  const float* in_w    = (const float*)d_in[2];
  const float* in_b    = (const float*)d_in[3];
  const float* ln_in_g = (const float*)d_in[4];
  const float* ln_in_b = (const float*)d_in[5];
  const float* ln_s_g  = (const float*)d_in[6];
  const float* ln_s_b  = (const float*)d_in[7];
  const float* ln_m_g  = (const float*)d_in[8];
  const float* ln_m_b  = (const float*)d_in[9];
  const float* q_w     = (const float*)d_in[10];
  const float* k_w     = (const float*)d_in[11];
  const float* v_w     = (const float*)d_in[12];
  const float* mlp_w1  = (const float*)d_in[13];
  const float* mlp_b1  = (const float*)d_in[14];
  const float* mlp_w2  = (const float*)d_in[15];
  const float* mlp_b2  = (const float*)d_in[16];
  const float* dec_w1  = (const float*)d_in[17];
  const float* dec_b1  = (const float*)d_in[18];
  const float* dec_w2  = (const float*)d_in[19];
  const float* dec_b2  = (const float*)d_in[20];
  const float* dec_w3  = (const float*)d_in[21];
  const float* dec_b3  = (const float*)d_in[22];

  char* ws = (char*)d_ws;
  size_t off = 0;
  auto alloc = [&](size_t bytes)->char*{
    char* p = ws + off; off = (off + bytes + 255) & ~(size_t)255; return p;
  };
  float* parts = (float*)alloc((size_t)8*64*4096*4);
  u16* in_wT = (u16*)alloc((size_t)256*4096*2);
  u16* q_wT  = (u16*)alloc((size_t)65536*2);
  u16* k_wT  = (u16*)alloc((size_t)65536*2);
  u16* v_wT  = (u16*)alloc((size_t)65536*2);
  u16* w1T   = (u16*)alloc((size_t)131072*2);
  u16* w2T   = (u16*)alloc((size_t)131072*2);
  u16* x_b   = (u16*)alloc((size_t)4096*256*2);
  u16* kk_b  = (u16*)alloc((size_t)4096*256*2);
  u16* vT_b  = (u16*)alloc((size_t)8*256*512*2);
  float* r2g = (float*)alloc((size_t)128*512*4);
  float* rpart = (float*)alloc((size_t)64*4096*4);

  float* out_slots = (float*)d_out;
  float* out_loss  = out_slots + 32768;

  hipLaunchKernelGGL(k_prep, dim3(368), dim3(256), 0, stream,
      in_w, q_w, k_w, v_w, mlp_w1, mlp_w2, in_wT, q_wT, k_wT, v_wT, w1T, w2T, out_loss);
  hipLaunchKernelGGL(k_colsum, dim3(64,4,8), dim3(256), 0, stream, hs, parts);
  hipLaunchKernelGGL(k_in_gemm_ln, dim3(64), dim3(1024), 0, stream,
      hs, in_wT, in_b, ln_in_g, ln_in_b, x_b);
  hipLaunchKernelGGL(k_kv, dim3(256), dim3(256), 0, stream, x_b, k_wT, v_wT, kk_b, vT_b);
  hipLaunchKernelGGL(k_slots, dim3(8), dim3(1024), 0, stream,
      oslots, kk_b, vT_b, q_wT, w1T, w2T,
      ln_s_g, ln_s_b, ln_m_g, ln_m_b, mlp_b1, mlp_b2, out_slots);
  hipLaunchKernelGGL(k_dec, dim3(128), dim3(256), 0, stream,
      out_slots, dec_w1, dec_b1, dec_w2, dec_b2, r2g);
  hipLaunchKernelGGL(k_loss_part, dim3(8,8), dim3(256), 0, stream,
      r2g, dec_w3, dec_b3, rpart);
  hipLaunchKernelGGL(k_loss_final, dim3(128), dim3(256), 0, stream,
      rpart, parts, out_loss);
}